// Round 5
// baseline (219.559 us; speedup 1.0000x reference)
//
#include <hip/hip_runtime.h>
#include <hip/hip_bf16.h>

#define TTLEN 2048
#define NCH   64
#define CLEN  32    // TTLEN / NCH

typedef unsigned short ushort_t;
typedef __attribute__((ext_vector_type(8))) short short8;
typedef __attribute__((ext_vector_type(4))) float f32x4;

__device__ __forceinline__ unsigned short f2bf(float f) {
    __hip_bfloat16 h = __float2bfloat16(f);
    return *reinterpret_cast<unsigned short*>(&h);
}
__device__ __forceinline__ float bf2f(unsigned int u16) {
    union { unsigned int i; float f; } v; v.i = u16 << 16; return v.f;
}

#define GLD_LDS16(gp, lp) __builtin_amdgcn_global_load_lds( \
    (const __attribute__((address_space(1))) void*)(gp),    \
    (__attribute__((address_space(3))) void*)(lp), 16, 0, 0)

// ------- fused: weights fp32->bf16 (blocks 0..1023) + time-shift mix (blocks 1024+) -------
__global__ void prep(const float* __restrict__ Wk, const float* __restrict__ Wv,
                     const float* __restrict__ Wr, const float* __restrict__ Wo,
                     ushort_t* __restrict__ Wall, ushort_t* __restrict__ Wob,
                     const float* __restrict__ x,
                     const float* __restrict__ tmk, const float* __restrict__ tmv,
                     const float* __restrict__ tmr,
                     ushort_t* __restrict__ xk, ushort_t* __restrict__ xv,
                     ushort_t* __restrict__ xr) {
    if (blockIdx.x < 1024) {
        int m = blockIdx.x >> 8;                       // 0..3
        const float* src = (m == 0) ? Wk : (m == 1) ? Wv : (m == 2) ? Wr : Wo;
        ushort_t* dst = (m == 3) ? Wob : Wall + (size_t)m * 262144;
        int i = (blockIdx.x & 255) * 256 + threadIdx.x;  // group of 4
        float4 v = *(const float4*)(src + (size_t)i * 4);
        union { unsigned short u[4]; uint2 p; } pk;
        pk.u[0] = f2bf(v.x); pk.u[1] = f2bf(v.y); pk.u[2] = f2bf(v.z); pk.u[3] = f2bf(v.w);
        *(uint2*)(dst + (size_t)i * 4) = pk.p;
        return;
    }
    int i   = (blockIdx.x - 1024) * 256 + threadIdx.x; // group of 4 channels
    int c4  = (i & 127) << 2;
    int row = i >> 7;                                  // b*T + t
    int t   = row & (TTLEN - 1);
    float4 xc = *(const float4*)(x + (size_t)row * 512 + c4);
    float4 xp = make_float4(0.f, 0.f, 0.f, 0.f);
    if (t != 0) xp = *(const float4*)(x + (size_t)(row - 1) * 512 + c4);
    size_t o = (size_t)row * 512 + c4;
    union { unsigned short u[4]; uint2 p; } pk;
    {
        float4 tv = *(const float4*)(tmk + c4);
        pk.u[0] = f2bf(xc.x * tv.x + xp.x * (1.f - tv.x));
        pk.u[1] = f2bf(xc.y * tv.y + xp.y * (1.f - tv.y));
        pk.u[2] = f2bf(xc.z * tv.z + xp.z * (1.f - tv.z));
        pk.u[3] = f2bf(xc.w * tv.w + xp.w * (1.f - tv.w));
        *(uint2*)(xk + o) = pk.p;
    }
    {
        float4 tv = *(const float4*)(tmv + c4);
        pk.u[0] = f2bf(xc.x * tv.x + xp.x * (1.f - tv.x));
        pk.u[1] = f2bf(xc.y * tv.y + xp.y * (1.f - tv.y));
        pk.u[2] = f2bf(xc.z * tv.z + xp.z * (1.f - tv.z));
        pk.u[3] = f2bf(xc.w * tv.w + xp.w * (1.f - tv.w));
        *(uint2*)(xv + o) = pk.p;
    }
    {
        float4 tv = *(const float4*)(tmr + c4);
        pk.u[0] = f2bf(xc.x * tv.x + xp.x * (1.f - tv.x));
        pk.u[1] = f2bf(xc.y * tv.y + xp.y * (1.f - tv.y));
        pk.u[2] = f2bf(xc.z * tv.z + xp.z * (1.f - tv.z));
        pk.u[3] = f2bf(xc.w * tv.w + xp.w * (1.f - tv.w));
        *(uint2*)(xr + o) = pk.p;
    }
}

// ---- 128x256 tile, 512 threads, DOUBLE-BUFFERED LDS (96KB), raw s_barrier + vmcnt(6) ----
// No __syncthreads in K-loop => no vmcnt(0) drain; iter k+1's 6 global_load_lds overlap
// iter k's MFMAs. 1 block/CU (96KB LDS) but intra-block pipeline hides load latency.
// MODE 0: fused k/v/r (N=1536, grid(6,128)); MODE 1: out-proj (N=512, grid(2,128))
template <int MODE>
__launch_bounds__(512, 2)
__global__ void gemm_db(const ushort_t* __restrict__ Axk, const ushort_t* __restrict__ Axv,
                        const ushort_t* __restrict__ Axr, const ushort_t* __restrict__ W,
                        const float* __restrict__ b0, const float* __restrict__ b1,
                        const float* __restrict__ b2,
                        ushort_t* __restrict__ o0, ushort_t* __restrict__ o1,
                        ushort_t* __restrict__ o2,
                        float* __restrict__ fout, const float* __restrict__ gamma) {
    __shared__ alignas(16) ushort_t As[2][128 * 64];   // 2 x 16 KB
    __shared__ alignas(16) ushort_t Bs[2][256 * 64];   // 2 x 32 KB
    const int tid  = threadIdx.x;
    const int lane = tid & 63;
    const int w    = tid >> 6;                      // 0..7
    const int wm   = (w >> 2) << 6;                 // 0 or 64
    const int wn   = (w & 3) << 6;                  // 0,64,128,192
    const int mBlk = blockIdx.y << 7;
    const int nBlk = blockIdx.x << 8;
    const int r16  = lane & 15, q = lane >> 4;
    const int rowInW = lane >> 3, ch = lane & 7;

    const int p = (MODE == 0) ? (blockIdx.x >> 1) : 0;   // projection band
    const ushort_t* A = (MODE == 1) ? Axk : (p == 0 ? Axk : (p == 1 ? Axv : Axr));

    f32x4 acc[4][4];
#pragma unroll
    for (int a = 0; a < 4; ++a)
#pragma unroll
        for (int b = 0; b < 4; ++b) acc[a][b] = (f32x4){0.f, 0.f, 0.f, 0.f};

    // stage K-slice k into buffer buf: 2 A-loads + 4 B-loads per thread (16B each)
    auto stage = [&](int k, int buf) {
        const ushort_t* Ag = A + (size_t)mBlk * 512 + k * 64;
        const ushort_t* Bg = W + (size_t)nBlk * 512 + k * 64;
#pragma unroll
        for (int i = 0; i < 2; ++i) {
            int baseRow = w * 16 + i * 8;
            int row = baseRow + rowInW;
            int gch = ch ^ (row & 7);
            GLD_LDS16(Ag + (size_t)row * 512 + gch * 8, &As[buf][baseRow * 64]);
        }
#pragma unroll
        for (int i = 0; i < 4; ++i) {
            int baseRow = w * 32 + i * 8;
            int row = baseRow + rowInW;
            int gch = ch ^ (row & 7);
            GLD_LDS16(Bg + (size_t)row * 512 + gch * 8, &Bs[buf][baseRow * 64]);
        }
    };

    stage(0, 0);   // prologue: 6 loads outstanding

#pragma unroll
    for (int k = 0; k < 8; ++k) {
        const int cur = k & 1;
        if (k < 7) {
            stage(k + 1, cur ^ 1);                       // +6 outstanding (12 total)
            asm volatile("s_waitcnt vmcnt(6)" ::: "memory");   // iter-k's 6 done
        } else {
            asm volatile("s_waitcnt vmcnt(0)" ::: "memory");
        }
        asm volatile("s_barrier" ::: "memory");          // all waves' iter-k loads in LDS

        short8 af[2][4], bfr[2][4];
#pragma unroll
        for (int s = 0; s < 2; ++s) {
#pragma unroll
            for (int mt = 0; mt < 4; ++mt) {
                int row = wm + mt * 16 + r16;
                af[s][mt] = *(const short8*)(&As[cur][row * 64 + (((s * 4 + q) ^ (r16 & 7)) << 3)]);
            }
#pragma unroll
            for (int nt = 0; nt < 4; ++nt) {
                int row = wn + nt * 16 + r16;
                bfr[s][nt] = *(const short8*)(&Bs[cur][row * 64 + (((s * 4 + q) ^ (r16 & 7)) << 3)]);
            }
        }
        asm volatile("s_waitcnt lgkmcnt(0)" ::: "memory");  // fragments in regs
        asm volatile("s_barrier" ::: "memory");             // buf[cur] free for iter k+1 writes

#pragma unroll
        for (int s = 0; s < 2; ++s)
#pragma unroll
            for (int mt = 0; mt < 4; ++mt)
#pragma unroll
                for (int nt = 0; nt < 4; ++nt)
                    acc[mt][nt] = __builtin_amdgcn_mfma_f32_16x16x32_bf16(
                        af[s][mt], bfr[s][nt], acc[mt][nt], 0, 0, 0);
    }

    if (MODE == 0) {
        const float* bias = (p == 0) ? b0 : (p == 1) ? b1 : b2;
        ushort_t* outp = (p == 0) ? o0 : (p == 1) ? o1 : o2;
#pragma unroll
        for (int mt = 0; mt < 4; ++mt) {
#pragma unroll
            for (int nt = 0; nt < 4; ++nt) {
                int nLocal = (nBlk & 511) + wn + nt * 16 + r16;
                float bv = bias[nLocal];
#pragma unroll
                for (int i = 0; i < 4; ++i) {
                    int row = mBlk + wm + mt * 16 + (q << 2) + i;
                    float v = acc[mt][nt][i] + bv;
                    if (p == 0) v = __expf(fminf(fmaxf(v, -60.f), 30.f));
                    else if (p == 2) v = 1.f / (1.f + __expf(-v));
                    outp[(size_t)row * 512 + nLocal] = f2bf(v);
                }
            }
        }
    } else {
#pragma unroll
        for (int mt = 0; mt < 4; ++mt) {
#pragma unroll
            for (int nt = 0; nt < 4; ++nt) {
                int col = nBlk + wn + nt * 16 + r16;
                float bv = b0[col];
#pragma unroll
                for (int i = 0; i < 4; ++i) {
                    int row = mBlk + wm + mt * 16 + (q << 2) + i;
                    float v = (acc[mt][nt][i] + bv) * gamma[row & (TTLEN - 1)];
                    fout[(size_t)row * 512 + col] = v;
                }
            }
        }
    }
}

// ---------------- scan phase A: per-chunk local (S, sum_k), bf16 in, 4 ch/thread ----
__global__ void scanA(const ushort_t* __restrict__ kb, const ushort_t* __restrict__ vb,
                      const float* __restrict__ tw, const float* __restrict__ alpha,
                      float* __restrict__ Sloc, float* __restrict__ Kloc) {
    int b = blockIdx.x >> 6, j = blockIdx.x & 63;
    int a0 = threadIdx.x * 4;                      // 128 threads x 4 channels
    int h = a0 >> 6;
    float r = tw[h * TTLEN + TTLEN - 2];
    int t0 = j * CLEN;
    size_t base = ((size_t)(b * TTLEN + t0)) * 512 + a0;
    const float* al = alpha + h * TTLEN + t0;
    float s[4] = {0.f, 0.f, 0.f, 0.f}, sk[4] = {0.f, 0.f, 0.f, 0.f};
#pragma unroll 8
    for (int it = 0; it < CLEN; ++it) {
        uint2 kk = *(const uint2*)(kb + base + (size_t)it * 512);
        uint2 vv = *(const uint2*)(vb + base + (size_t)it * 512);
        float kf[4] = {bf2f(kk.x & 0xffff), bf2f(kk.x >> 16),
                       bf2f(kk.y & 0xffff), bf2f(kk.y >> 16)};
        float vf[4] = {bf2f(vv.x & 0xffff), bf2f(vv.x >> 16),
                       bf2f(vv.y & 0xffff), bf2f(vv.y >> 16)};
        float av = al[it];
#pragma unroll
        for (int c = 0; c < 4; ++c) {
            sk[c] += kf[c];
            s[c] = fmaf(r, s[c], av * kf[c] * vf[c]);
        }
    }
    int o = (b * NCH + j) * 512 + a0;
    *(float4*)(Sloc + o) = make_float4(s[0], s[1], s[2], s[3]);
    *(float4*)(Kloc + o) = make_float4(sk[0], sk[1], sk[2], sk[3]);
}

// ---------------- scan mid: exclusive prefix across chunks ----------------
__global__ void scanMid(const float* __restrict__ tw,
                        const float* __restrict__ Sloc, const float* __restrict__ Kloc,
                        float* __restrict__ Sin, float* __restrict__ Kin) {
    int idx = blockIdx.x * 256 + threadIdx.x;   // 4096 = B*A
    int a = idx & 511, b = idx >> 9;
    int h = a >> 6;
    float r = tw[h * TTLEN + TTLEN - 2];
    float rL = r;
#pragma unroll
    for (int i = 0; i < 5; ++i) rL *= rL;       // r^32
    float cs = 0.f, ck = 0.f;
#pragma unroll
    for (int j = 0; j < NCH; ++j) {
        int o = (b * NCH + j) * 512 + a;
        Sin[o] = cs; Kin[o] = ck;
        cs = fmaf(rL, cs, Sloc[o]);
        ck += Kloc[o];
    }
}

// ------------- scan phase B: replay with true prefix, emit rwkv bf16, 4 ch/thread ----
__global__ void scanB(const ushort_t* __restrict__ kb, const ushort_t* __restrict__ vb,
                      const ushort_t* __restrict__ rb,
                      const float* __restrict__ tw, const float* __restrict__ alpha,
                      const float* __restrict__ beta,
                      const float* __restrict__ Sin, const float* __restrict__ Kin,
                      ushort_t* __restrict__ rwkv) {
    int b = blockIdx.x >> 6, j = blockIdx.x & 63;
    int a0 = threadIdx.x * 4;
    int h = a0 >> 6;
    float r = tw[h * TTLEN + TTLEN - 2];
    int t0 = j * CLEN;
    size_t base = ((size_t)(b * TTLEN + t0)) * 512 + a0;
    const float* al = alpha + h * TTLEN + t0;
    const float* bt = beta + h * TTLEN + t0;
    int o = (b * NCH + j) * 512 + a0;
    float4 sv = *(const float4*)(Sin + o);
    float4 kv = *(const float4*)(Kin + o);
    float s[4] = {sv.x, sv.y, sv.z, sv.w};
    float sk[4] = {kv.x, kv.y, kv.z, kv.w};
#pragma unroll 4
    for (int it = 0; it < CLEN; ++it) {
        uint2 kk = *(const uint2*)(kb + base + (size_t)it * 512);
        uint2 vv = *(const uint2*)(vb + base + (size_t)it * 512);
        uint2 rr = *(const uint2*)(rb + base + (size_t)it * 512);
        float kf[4] = {bf2f(kk.x & 0xffff), bf2f(kk.x >> 16),
                       bf2f(kk.y & 0xffff), bf2f(kk.y >> 16)};
        float vf[4] = {bf2f(vv.x & 0xffff), bf2f(vv.x >> 16),
                       bf2f(vv.y & 0xffff), bf2f(vv.y >> 16)};
        float rf[4] = {bf2f(rr.x & 0xffff), bf2f(rr.x >> 16),
                       bf2f(rr.y & 0xffff), bf2f(rr.y >> 16)};
        float av = al[it], btv = bt[it];
        unsigned short u[4];
#pragma unroll
        for (int c = 0; c < 4; ++c) {
            sk[c] += kf[c];
            s[c] = fmaf(r, s[c], av * kf[c] * vf[c]);
            u[c] = f2bf(rf[c] * btv * s[c] / sk[c]);
        }
        uint2 outw;
        outw.x = ((unsigned int)u[1] << 16) | u[0];
        outw.y = ((unsigned int)u[3] << 16) | u[2];
        *(uint2*)(rwkv + base + (size_t)it * 512) = outw;
    }
}

extern "C" void kernel_launch(void* const* d_in, const int* in_sizes, int n_in,
                              void* d_out, int out_size, void* d_ws, size_t ws_size,
                              hipStream_t stream) {
    const float* x   = (const float*)d_in[0];
    const float* tw  = (const float*)d_in[1];
    const float* ta  = (const float*)d_in[2];
    const float* tb  = (const float*)d_in[3];
    const float* tg  = (const float*)d_in[4];
    const float* tmk = (const float*)d_in[5];
    const float* tmv = (const float*)d_in[6];
    const float* tmr = (const float*)d_in[7];
    const float* Wk  = (const float*)d_in[8];
    const float* bk  = (const float*)d_in[9];
    const float* Wv  = (const float*)d_in[10];
    const float* bv  = (const float*)d_in[11];
    const float* Wr  = (const float*)d_in[12];
    const float* br  = (const float*)d_in[13];
    const float* Wo  = (const float*)d_in[14];
    const float* bo  = (const float*)d_in[15];

    char* ws = (char*)d_ws;
    ushort_t* Wall = (ushort_t*)(ws + 0);            // [1536][512] bf16 (Wk;Wv;Wr)
    ushort_t* Wob  = (ushort_t*)(ws + 1572864);      // [512][512] bf16
    ushort_t* xk   = (ushort_t*)(ws + 2097152);      // 16.78 MB each
    ushort_t* xv   = (ushort_t*)(ws + 18874368);
    ushort_t* xr   = (ushort_t*)(ws + 35651584);
    ushort_t* kb   = (ushort_t*)(ws + 52428800);
    ushort_t* vb   = (ushort_t*)(ws + 69206016);
    ushort_t* rb   = (ushort_t*)(ws + 85983232);
    ushort_t* rwkv = xk;                             // xk dead after gemm<0>
    float* Sloc = (float*)(ws + 102760448);          // 1 MB each
    float* Kloc = (float*)(ws + 103809024);
    float* Sin  = (float*)(ws + 104857600);
    float* Kin  = (float*)(ws + 105906176);

    prep<<<9216, 256, 0, stream>>>(Wk, Wv, Wr, Wo, Wall, Wob,
                                   x, tmk, tmv, tmr, xk, xv, xr);

    gemm_db<0><<<dim3(6, 128), 512, 0, stream>>>(xk, xv, xr, Wall, bk, bv, br,
                                                 kb, vb, rb, nullptr, nullptr);

    scanA<<<512, 128, 0, stream>>>(kb, vb, tw, ta, Sloc, Kloc);
    scanMid<<<16, 256, 0, stream>>>(tw, Sloc, Kloc, Sin, Kin);
    scanB<<<512, 128, 0, stream>>>(kb, vb, rb, tw, ta, tb, Sin, Kin, rwkv);

    gemm_db<1><<<dim3(2, 128), 512, 0, stream>>>(rwkv, nullptr, nullptr, Wob, bo, nullptr,
                                                 nullptr, nullptr, nullptr, nullptr,
                                                 (float*)d_out, tg);
}